// Round 7
// baseline (501.572 us; speedup 1.0000x reference)
//
#include <hip/hip_runtime.h>

constexpr int NN   = 100000;
constexpr int NE   = 3200000;
constexpr int FIN  = 512;
constexpr int FH   = 16;
constexpr int FOUT = 64;

constexpr int BSZ  = 64;                      // agg node-group size
constexpr int KAGG = (NN + BSZ - 1) / BSZ;    // 1563 agg blocks
constexpr int NB   = 512;                     // binning blocks
constexpr int CHUNK = NE / NB;                // 6250 edges per block (exact)
constexpr int CAP  = 4096;                    // LDS staging cap per agg group

constexpr int BKB  = 10;                      // coarse bucket shift (1024 nodes)
constexpr int NBK  = (NN + 1023) >> 10;       // 98 coarse buckets

constexpr int G1B = 1024;                     // gemm1 grid: 4 blocks/CU exactly
constexpr int G1T = 128;                      // gemm1 threads/block (2 waves)
constexpr int NPB = 98;                       // nodes per gemm1 block

// coarse per-block bucket counts: M[k*NB + b], 98 x 512
__global__ __launch_bounds__(256) void k_cntA(const int* __restrict__ ei, int* __restrict__ M) {
    __shared__ int h[NBK];
    int t = threadIdx.x, b = blockIdx.x;
    if (t < NBK) h[t] = 0;
    __syncthreads();
    int e0 = b * CHUNK;
    for (int e = e0 + t; e < e0 + CHUNK; e += 256)
        atomicAdd(&h[ei[NE + e] >> BKB], 1);
    __syncthreads();
    if (t < NBK) M[t * NB + b] = h[t];
}

// per bucket-row exclusive scan over the NB blocks, in place; bucket totals out.
__global__ __launch_bounds__(256) void k_scanA(int* __restrict__ M, int* __restrict__ btot) {
    int k = blockIdx.x, t = threadIdx.x;
    int2* row = (int2*)(M + (size_t)k * NB);
    int2 v = row[t];                       // 256 threads x 2 = NB
    int s = v.x + v.y;
    int lane = t & 63, wid = t >> 6;
    int ps = s;
    #pragma unroll
    for (int off = 1; off < 64; off <<= 1) {
        int u = __shfl_up(ps, off, 64);
        if (lane >= off) ps += u;
    }
    __shared__ int wsum[4];
    if (lane == 63) wsum[wid] = ps;
    __syncthreads();
    int base = 0;
    for (int w = 0; w < wid; ++w) base += wsum[w];
    int excl = base + ps - s;
    int2 o; o.x = excl; o.y = excl + v.x;
    row[t] = o;
    if (t == 255) btot[k] = excl + s;
}

// exclusive scan of 98 coarse-bucket totals -> bstartA[NBK+1]; single wave, 2 elems/thread
__global__ __launch_bounds__(64) void k_scanBA(const int* __restrict__ btot, int* __restrict__ bstartA) {
    int t = threadIdx.x;
    int i0 = 2 * t, i1 = 2 * t + 1;
    int c0 = (i0 < NBK) ? btot[i0] : 0;
    int c1 = (i1 < NBK) ? btot[i1] : 0;
    int s = c0 + c1;
    int ps = s;
    #pragma unroll
    for (int off = 1; off < 64; off <<= 1) {
        int u = __shfl_up(ps, off, 64);
        if (t >= off) ps += u;
    }
    int excl = ps - s;
    if (i0 < NBK) bstartA[i0] = excl;
    if (i1 < NBK) bstartA[i1] = excl + c0;
    if (t == 0) bstartA[NBK] = NE;
}

// coarse scatter: rec1[pos] = (src<<10) | (d & 1023). Runs per (block,bucket) ~64
// edges = 256B -> coalesced writes; LDS cursors only.
__global__ __launch_bounds__(256) void k_scatA(const int* __restrict__ ei,
                                               const int* __restrict__ M,
                                               const int* __restrict__ bstartA,
                                               int* __restrict__ rec1) {
    __shared__ int cur[NBK];
    int t = threadIdx.x, b = blockIdx.x;
    if (t < NBK) cur[t] = bstartA[t] + M[t * NB + b];
    __syncthreads();
    int e0 = b * CHUNK;
    for (int e = e0 + t; e < e0 + CHUNK; e += 256) {
        int s = ei[e];
        int d = ei[NE + e];
        int pos = atomicAdd(&cur[d >> BKB], 1);
        rec1[pos] = (s << BKB) | (d & 1023);
    }
}

// per-coarse-bucket counting sort by d_local -> full CSR by destination node.
// Emits row_ptr[node] and dis[node]; scatter window ~131 KB (L2-local).
__global__ __launch_bounds__(256) void k_sortA(const int* __restrict__ rec1,
                                               const int* __restrict__ bstartA,
                                               int* __restrict__ rec2,
                                               int* __restrict__ row_ptr,
                                               float* __restrict__ dis) {
    __shared__ int h[1024];
    __shared__ int cur[1024];
    __shared__ int wsum[4];
    int t = threadIdx.x, k = blockIdx.x;
    *(int4*)&h[4 * t] = make_int4(0, 0, 0, 0);
    __syncthreads();
    int e0 = bstartA[k], e1 = bstartA[k + 1];
    for (int e = e0 + t; e < e1; e += 256)
        atomicAdd(&h[rec1[e] & 1023], 1);
    __syncthreads();
    // block-wide exclusive scan of the 1024 counts (4 per thread)
    int i0 = 4 * t;
    int c0 = h[i0], c1 = h[i0 + 1], c2 = h[i0 + 2], c3 = h[i0 + 3];
    int s = c0 + c1 + c2 + c3;
    int lane = t & 63, wid = t >> 6;
    int ps = s;
    #pragma unroll
    for (int off = 1; off < 64; off <<= 1) {
        int u = __shfl_up(ps, off, 64);
        if (lane >= off) ps += u;
    }
    if (lane == 63) wsum[wid] = ps;
    __syncthreads();
    int base = 0;
    for (int w = 0; w < wid; ++w) base += wsum[w];
    int ex = base + ps - s;
    int e0x = ex, e1x = ex + c0, e2x = e1x + c1, e3x = e2x + c2;
    cur[i0] = e0x; cur[i0 + 1] = e1x; cur[i0 + 2] = e2x; cur[i0 + 3] = e3x;
    int node = (k << BKB) + i0;
    if (node + 3 < NN) {
        *(int4*)&row_ptr[node] = make_int4(e0 + e0x, e0 + e1x, e0 + e2x, e0 + e3x);
        *(float4*)&dis[node]   = make_float4(rsqrtf((float)c0 + 1.f), rsqrtf((float)c1 + 1.f),
                                             rsqrtf((float)c2 + 1.f), rsqrtf((float)c3 + 1.f));
    } else {
        int exs[4] = {e0x, e1x, e2x, e3x};
        int cs[4]  = {c0, c1, c2, c3};
        #pragma unroll
        for (int j = 0; j < 4; ++j)
            if (node + j < NN) { row_ptr[node + j] = e0 + exs[j]; dis[node + j] = rsqrtf((float)cs[j] + 1.f); }
    }
    __syncthreads();
    for (int e = e0 + t; e < e1; e += 256) {
        int r = rec1[e];
        int pos = atomicAdd(&cur[r & 1023], 1);
        rec2[e0 + pos] = r >> BKB;        // plain src
    }
    if (k == 0 && t == 0) row_ptr[NN] = NE;
}

// consume one 64B x-line (16 k values) against 16 LDS W-rows (broadcast reads)
__device__ __forceinline__ void cons16(float acc[FH], float4 a0, float4 a1, float4 a2, float4 a3,
                                       const float* __restrict__ wrow) {
    float xs[16] = {a0.x, a0.y, a0.z, a0.w, a1.x, a1.y, a1.z, a1.w,
                    a2.x, a2.y, a2.z, a2.w, a3.x, a3.y, a3.z, a3.w};
    #pragma unroll
    for (int c = 0; c < 16; ++c) {
        float xv = xs[c];
        const float* w = &wrow[c * FH];
        #pragma unroll
        for (int jb = 0; jb < 4; ++jb) {
            float4 wv = *(const float4*)&w[jb * 4];
            acc[jb * 4 + 0] += xv * wv.x;
            acc[jb * 4 + 1] += xv * wv.y;
            acc[jb * 4 + 2] += xv * wv.z;
            acc[jb * 4 + 3] += xv * wv.w;
        }
    }
}

// vp1 = dis * (x @ W1): one node per thread; depth-2 pipeline; W1 in LDS (broadcast).
// Grid 1024 x 128: exactly 4 blocks/CU, 8 waves/CU.
__global__ __launch_bounds__(G1T) void k_gemm1(const float* __restrict__ x,
                                               const float* __restrict__ W1,
                                               const float* __restrict__ dis,
                                               float* __restrict__ vp1) {
    __shared__ float ws[FIN * FH];        // 32 KB
    int t = threadIdx.x;
    #pragma unroll
    for (int i = 0; i < 16; ++i)          // 16 * 128 * 4 = 8192 floats
        *(float4*)&ws[i * 512 + t * 4] = *(const float4*)&W1[i * 512 + t * 4];
    int node = blockIdx.x * NPB + t;
    bool live = (t < NPB) && (node < NN);
    int n = live ? node : NN - 1;
    const float* xr = x + (size_t)n * FIN;
    float acc[FH];
    #pragma unroll
    for (int j = 0; j < FH; ++j) acc[j] = 0.f;
    float4 A0 = *(const float4*)&xr[0],  A1 = *(const float4*)&xr[4],
           A2 = *(const float4*)&xr[8],  A3 = *(const float4*)&xr[12];
    float4 B0 = *(const float4*)&xr[16], B1 = *(const float4*)&xr[20],
           B2 = *(const float4*)&xr[24], B3 = *(const float4*)&xr[28];
    __syncthreads();
    #pragma unroll 1
    for (int k0 = 0; k0 + 48 <= FIN; k0 += 32) {
        float4 C0 = *(const float4*)&xr[k0 + 32], C1 = *(const float4*)&xr[k0 + 36],
               C2 = *(const float4*)&xr[k0 + 40], C3 = *(const float4*)&xr[k0 + 44];
        cons16(acc, A0, A1, A2, A3, &ws[k0 * FH]);
        A0 = C0; A1 = C1; A2 = C2; A3 = C3;
        float4 D0 = *(const float4*)&xr[k0 + 48], D1 = *(const float4*)&xr[k0 + 52],
               D2 = *(const float4*)&xr[k0 + 56], D3 = *(const float4*)&xr[k0 + 60];
        cons16(acc, B0, B1, B2, B3, &ws[(k0 + 16) * FH]);
        B0 = D0; B1 = D1; B2 = D2; B3 = D3;
    }
    cons16(acc, A0, A1, A2, A3, &ws[(FIN - 32) * FH]);
    cons16(acc, B0, B1, B2, B3, &ws[(FIN - 16) * FH]);
    if (live) {
        float dv = dis[node];
        #pragma unroll
        for (int jb = 0; jb < 4; ++jb)
            *(float4*)&vp1[(size_t)node * FH + jb * 4] =
                make_float4(dv * acc[jb * 4], dv * acc[jb * 4 + 1],
                            dv * acc[jb * 4 + 2], dv * acc[jb * 4 + 3]);
    }
}

// CSR register-accumulating gather, 4 lanes/node, unroll-8 independent 64B-line gathers
__device__ __forceinline__ float4 seg_gather(const int* __restrict__ recs,   // LDS copy
                                             const int* __restrict__ gsrc,   // global fallback
                                             int a, int b, int nst,
                                             const float* __restrict__ vp, int q) {
    float4 acc = make_float4(0.f, 0.f, 0.f, 0.f);
    int blds = b < nst ? b : nst;
    int i = a;
    for (; i + 8 <= blds; i += 8) {
        int r0 = recs[i],     r1 = recs[i + 1], r2 = recs[i + 2], r3 = recs[i + 3];
        int r4 = recs[i + 4], r5 = recs[i + 5], r6 = recs[i + 6], r7 = recs[i + 7];
        float4 v0 = *(const float4*)&vp[(size_t)r0 * FH + q * 4];
        float4 v1 = *(const float4*)&vp[(size_t)r1 * FH + q * 4];
        float4 v2 = *(const float4*)&vp[(size_t)r2 * FH + q * 4];
        float4 v3 = *(const float4*)&vp[(size_t)r3 * FH + q * 4];
        float4 v4 = *(const float4*)&vp[(size_t)r4 * FH + q * 4];
        float4 v5 = *(const float4*)&vp[(size_t)r5 * FH + q * 4];
        float4 v6 = *(const float4*)&vp[(size_t)r6 * FH + q * 4];
        float4 v7 = *(const float4*)&vp[(size_t)r7 * FH + q * 4];
        acc.x += ((v0.x + v1.x) + (v2.x + v3.x)) + ((v4.x + v5.x) + (v6.x + v7.x));
        acc.y += ((v0.y + v1.y) + (v2.y + v3.y)) + ((v4.y + v5.y) + (v6.y + v7.y));
        acc.z += ((v0.z + v1.z) + (v2.z + v3.z)) + ((v4.z + v5.z) + (v6.z + v7.z));
        acc.w += ((v0.w + v1.w) + (v2.w + v3.w)) + ((v4.w + v5.w) + (v6.w + v7.w));
    }
    for (; i < blds; ++i) {
        int r0 = recs[i];
        float4 v0 = *(const float4*)&vp[(size_t)r0 * FH + q * 4];
        acc.x += v0.x; acc.y += v0.y; acc.z += v0.z; acc.w += v0.w;
    }
    for (int j = (a > nst ? a : nst); j < b; ++j) {   // overflow fallback (group > CAP)
        int r0 = gsrc[j];
        float4 v0 = *(const float4*)&vp[(size_t)r0 * FH + q * 4];
        acc.x += v0.x; acc.y += v0.y; acc.z += v0.z; acc.w += v0.w;
    }
    return acc;
}

// layer-1: vp2[d] = dis[d] * relu(dis[d]*(sum_s vp1[s] + vp1[d]) + b1)
__global__ __launch_bounds__(256) void k_agg1(const int* __restrict__ rec2,
                                              const int* __restrict__ row_ptr,
                                              const float* __restrict__ dis,
                                              const float* __restrict__ vp1,
                                              const float* __restrict__ b1,
                                              float* __restrict__ vp2) {
    __shared__ int recs[CAP];                 // 16 KB
    int t = threadIdx.x, k = blockIdx.x;
    int n0 = k * BSZ;
    int nend = n0 + BSZ < NN ? n0 + BSZ : NN;
    int e0 = row_ptr[n0], e1 = row_ptr[nend];
    int len = e1 - e0, nst = len < CAP ? len : CAP;
    for (int i = t; i < nst; i += 256) recs[i] = rec2[e0 + i];
    __syncthreads();                          // no barriers after: early-exit safe
    int slot = t >> 2, q = t & 3;
    int node = n0 + slot;
    if (node >= NN) return;
    int a = row_ptr[node] - e0;
    int b = row_ptr[node + 1] - e0;
    float4 acc = seg_gather(recs, rec2 + e0, a, b, nst, vp1, q);
    float dv = dis[node];
    float4 self = *(const float4*)&vp1[(size_t)node * FH + q * 4];
    float4 bb   = *(const float4*)&b1[q * 4];
    float4 o;
    o.x = dv * fmaxf(dv * (acc.x + self.x) + bb.x, 0.f);
    o.y = dv * fmaxf(dv * (acc.y + self.y) + bb.y, 0.f);
    o.z = dv * fmaxf(dv * (acc.z + self.z) + bb.z, 0.f);
    o.w = dv * fmaxf(dv * (acc.w + self.w) + bb.w, 0.f);
    *(float4*)&vp2[(size_t)node * FH + q * 4] = o;
}

// layer-2: a16 = dis[d]*(sum_s vp2[s] + vp2[d]); out = relu(a16 @ W2 + b2)
__global__ __launch_bounds__(256) void k_agg2(const int* __restrict__ rec2,
                                              const int* __restrict__ row_ptr,
                                              const float* __restrict__ dis,
                                              const float* __restrict__ vp2,
                                              const float* __restrict__ W2,
                                              const float* __restrict__ b2,
                                              float* __restrict__ out) {
    __shared__ int   recs[CAP];               // 16 KB
    __shared__ float a16[BSZ * FH];           // 4 KB
    __shared__ float ws[FH * FOUT];           // 4 KB
    int t = threadIdx.x, k = blockIdx.x;
    *(float4*)&ws[t * 4] = *(const float4*)&W2[t * 4];   // 256*4 = FH*FOUT
    int n0 = k * BSZ;
    int nend = n0 + BSZ < NN ? n0 + BSZ : NN;
    int e0 = row_ptr[n0], e1 = row_ptr[nend];
    int len = e1 - e0, nst = len < CAP ? len : CAP;
    for (int i = t; i < nst; i += 256) recs[i] = rec2[e0 + i];
    __syncthreads();
    int slot = t >> 2, q = t & 3;
    int node = n0 + slot;
    float4 r = make_float4(0.f, 0.f, 0.f, 0.f);
    if (node < NN) {
        int a = row_ptr[node] - e0;
        int b = row_ptr[node + 1] - e0;
        float4 acc = seg_gather(recs, rec2 + e0, a, b, nst, vp2, q);
        float dv = dis[node];
        float4 self = *(const float4*)&vp2[(size_t)node * FH + q * 4];
        r.x = dv * (acc.x + self.x);
        r.y = dv * (acc.y + self.y);
        r.z = dv * (acc.z + self.z);
        r.w = dv * (acc.w + self.w);
    }
    *(float4*)&a16[slot * FH + q * 4] = r;
    __syncthreads();
    int j = t & 63;
    float bj = b2[j];
    float wreg[FH];
    #pragma unroll
    for (int kk = 0; kk < FH; ++kk) wreg[kk] = ws[kk * FOUT + j];
    for (int n = t >> 6; n < BSZ; n += 4) {
        int node2 = n0 + n;
        if (node2 >= NN) break;
        const float* ar = &a16[n * FH];
        float s = 0.f;
        #pragma unroll
        for (int kk = 0; kk < FH; ++kk) s += ar[kk] * wreg[kk];
        out[(size_t)node2 * FOUT + j] = fmaxf(s + bj, 0.f);
    }
}

extern "C" void kernel_launch(void* const* d_in, const int* in_sizes, int n_in,
                              void* d_out, int out_size, void* d_ws, size_t ws_size,
                              hipStream_t stream) {
    const float* x  = (const float*)d_in[0];
    const int*   ei = (const int*)d_in[1];
    const float* W1 = (const float*)d_in[2];
    const float* b1 = (const float*)d_in[3];
    const float* W2 = (const float*)d_in[4];
    const float* b2 = (const float*)d_in[5];
    float* out = (float*)d_out;

    // workspace (~27 MB). rec1's 12.8MB is dead after k_sortA and is reused
    // for vp1 (6.4MB) + vp2 (6.4MB): stream-ordered, no overlap hazard.
    char* p = (char*)d_ws;
    int*   M       = (int*)p;    p += (size_t)NBK * NB * 4;    // 200 KB
    int*   btot    = (int*)p;    p += 128 * 4;
    int*   bstartA = (int*)p;    p += 128 * 4;
    char*  bufA    = p;          p += (size_t)NE * 4;          // 12.8 MB (rec1 -> vp1+vp2)
    int*   rec2    = (int*)p;    p += (size_t)NE * 4;          // 12.8 MB
    int*   row_ptr = (int*)p;    p += 100368 * 4;              // NN+1 padded
    float* dis     = (float*)p;  p += 100368 * 4;

    int*   rec1 = (int*)bufA;
    float* vp1  = (float*)bufA;
    float* vp2  = (float*)(bufA + (size_t)NN * FH * 4);

    k_cntA  <<<NB,  256, 0, stream>>>(ei, M);
    k_scanA <<<NBK, 256, 0, stream>>>(M, btot);
    k_scanBA<<<1,   64,  0, stream>>>(btot, bstartA);
    k_scatA <<<NB,  256, 0, stream>>>(ei, M, bstartA, rec1);
    k_sortA <<<NBK, 256, 0, stream>>>(rec1, bstartA, rec2, row_ptr, dis);

    k_gemm1 <<<G1B, G1T, 0, stream>>>(x, W1, dis, vp1);
    k_agg1  <<<KAGG, 256, 0, stream>>>(rec2, row_ptr, dis, vp1, b1, vp2);
    k_agg2  <<<KAGG, 256, 0, stream>>>(rec2, row_ptr, dis, vp2, W2, b2, out);
}

// Round 8
// 469.869 us; speedup vs baseline: 1.0675x; 1.0675x over previous
//
#include <hip/hip_runtime.h>

constexpr int NN   = 100000;
constexpr int NE   = 3200000;
constexpr int FIN  = 512;
constexpr int FH   = 16;
constexpr int FOUT = 64;

constexpr int BSH = 6;                     // bucket shift (64 nodes/bucket)
constexpr int BSZ = 64;
constexpr int K   = (NN + BSZ - 1) / BSZ;  // 1563 buckets
constexpr int NB  = 512;                   // binning blocks
constexpr int CHUNK = NE / NB;             // 6250 edges per block (exact)
constexpr int CAP = 4096;                  // LDS staging cap per bucket (mean 2048, sigma ~45)

constexpr int G1B = 1024;                  // gemm1 grid: 4 blocks/CU exactly
constexpr int G1T = 128;                   // gemm1 threads/block (2 waves)
constexpr int NPB = 98;                    // nodes per gemm1 block

// per-block bucket counts: M[k*NB + b]. 4 edges/thread/iter: independent loads,
// then independent LDS atomics (latency-bound loop -> MLP 4).
__global__ __launch_bounds__(256) void k_cnt(const int* __restrict__ ei, int* __restrict__ M) {
    __shared__ int h[K];
    int t = threadIdx.x, b = blockIdx.x;
    for (int i = t; i < K; i += 256) h[i] = 0;
    __syncthreads();
    int e0 = b * CHUNK, eend = e0 + CHUNK;
    int e = e0 + 4 * t;
    for (; e + 4 <= eend; e += 1024) {
        int d0 = ei[NE + e],     d1 = ei[NE + e + 1];
        int d2 = ei[NE + e + 2], d3 = ei[NE + e + 3];
        atomicAdd(&h[d0 >> BSH], 1);
        atomicAdd(&h[d1 >> BSH], 1);
        atomicAdd(&h[d2 >> BSH], 1);
        atomicAdd(&h[d3 >> BSH], 1);
    }
    for (int ee = e; ee < eend && ee < e + 4; ++ee)
        atomicAdd(&h[ei[NE + ee] >> BSH], 1);
    __syncthreads();
    for (int i = t; i < K; i += 256) M[i * NB + b] = h[i];
}

// per bucket-row exclusive scan over the NB blocks, in place; bucket totals out.
__global__ __launch_bounds__(256) void k_scanM(int* __restrict__ M, int* __restrict__ btot) {
    int k = blockIdx.x, t = threadIdx.x;
    int2* row = (int2*)(M + (size_t)k * NB);
    int2 v = row[t];                       // 256 threads x 2 = NB
    int s = v.x + v.y;
    int lane = t & 63, wid = t >> 6;
    int ps = s;
    #pragma unroll
    for (int off = 1; off < 64; off <<= 1) {
        int u = __shfl_up(ps, off, 64);
        if (lane >= off) ps += u;
    }
    __shared__ int wsum[4];
    if (lane == 63) wsum[wid] = ps;
    __syncthreads();
    int base = 0;
    for (int w = 0; w < wid; ++w) base += wsum[w];
    int excl = base + ps - s;
    int2 o; o.x = excl; o.y = excl + v.x;
    row[t] = o;
    if (t == 255) btot[k] = excl + s;
}

// exclusive scan of bucket totals (K=1563) -> bstart[K+1]; 2 elems/thread
__global__ __launch_bounds__(1024) void k_scanB(const int* __restrict__ btot, int* __restrict__ bstart) {
    int t = threadIdx.x;
    int i0 = 2 * t, i1 = 2 * t + 1;
    int c0 = (i0 < K) ? btot[i0] : 0;
    int c1 = (i1 < K) ? btot[i1] : 0;
    int s = c0 + c1;
    int lane = t & 63, wid = t >> 6;
    int ps = s;
    #pragma unroll
    for (int off = 1; off < 64; off <<= 1) {
        int u = __shfl_up(ps, off, 64);
        if (lane >= off) ps += u;
    }
    __shared__ int wsum[16];
    if (lane == 63) wsum[wid] = ps;
    __syncthreads();
    int base = 0;
    for (int w = 0; w < wid; ++w) base += wsum[w];
    int excl = base + ps - s;
    if (i0 < K) bstart[i0] = excl;
    if (i1 < K) bstart[i1] = excl + c0;
    if (t == 0) bstart[K] = NE;
}

// deterministic scatter: rec1[pos] = (src<<6) | d_local; per-block cursors in LDS only.
// 4-wide batched: 8 loads, 4 atomics, 4 stores per iteration, all independent.
__global__ __launch_bounds__(256) void k_scatter2(const int* __restrict__ ei,
                                                  const int* __restrict__ M,
                                                  const int* __restrict__ bstart,
                                                  int* __restrict__ rec) {
    __shared__ int cur[K];
    int t = threadIdx.x, b = blockIdx.x;
    for (int i = t; i < K; i += 256) cur[i] = bstart[i] + M[i * NB + b];
    __syncthreads();
    int e0 = b * CHUNK, eend = e0 + CHUNK;
    int e = e0 + 4 * t;
    for (; e + 4 <= eend; e += 1024) {
        int s0 = ei[e],     s1 = ei[e + 1],     s2 = ei[e + 2],     s3 = ei[e + 3];
        int d0 = ei[NE + e], d1 = ei[NE + e + 1], d2 = ei[NE + e + 2], d3 = ei[NE + e + 3];
        int p0 = atomicAdd(&cur[d0 >> BSH], 1);
        int p1 = atomicAdd(&cur[d1 >> BSH], 1);
        int p2 = atomicAdd(&cur[d2 >> BSH], 1);
        int p3 = atomicAdd(&cur[d3 >> BSH], 1);
        rec[p0] = (s0 << BSH) | (d0 & (BSZ - 1));
        rec[p1] = (s1 << BSH) | (d1 & (BSZ - 1));
        rec[p2] = (s2 << BSH) | (d2 & (BSZ - 1));
        rec[p3] = (s3 << BSH) | (d3 & (BSZ - 1));
    }
    for (int ee = e; ee < eend && ee < e + 4; ++ee) {
        int s = ei[ee];
        int d = ei[NE + ee];
        int pos = atomicAdd(&cur[d >> BSH], 1);
        rec[pos] = (s << BSH) | (d & (BSZ - 1));
    }
}

// in-bucket counting sort by d_local -> full CSR by destination node (rec2 holds plain src).
// Both per-edge loops 4-wide batched.
__global__ __launch_bounds__(256) void k_sort2(const int* __restrict__ rec1,
                                               const int* __restrict__ bstart,
                                               int* __restrict__ rec2,
                                               int* __restrict__ row_ptr,
                                               float* __restrict__ dis) {
    __shared__ int h[BSZ];
    __shared__ int cur[BSZ];
    int t = threadIdx.x, k = blockIdx.x;
    if (t < BSZ) h[t] = 0;
    __syncthreads();
    int e0 = bstart[k], e1 = bstart[k + 1];
    {
        int e = e0 + 4 * t;
        for (; e + 4 <= e1; e += 1024) {
            int r0 = rec1[e], r1 = rec1[e + 1], r2 = rec1[e + 2], r3 = rec1[e + 3];
            atomicAdd(&h[r0 & (BSZ - 1)], 1);
            atomicAdd(&h[r1 & (BSZ - 1)], 1);
            atomicAdd(&h[r2 & (BSZ - 1)], 1);
            atomicAdd(&h[r3 & (BSZ - 1)], 1);
        }
        for (int ee = e; ee < e1 && ee < e + 4; ++ee)
            atomicAdd(&h[rec1[ee] & (BSZ - 1)], 1);
    }
    __syncthreads();
    if (t < BSZ) {                         // wave 0: exclusive scan of 64 counts
        int c = h[t];
        int ps = c;
        #pragma unroll
        for (int off = 1; off < 64; off <<= 1) {
            int u = __shfl_up(ps, off, 64);
            if (t >= off) ps += u;
        }
        int excl = ps - c;
        cur[t] = excl;
        int node = k * BSZ + t;
        if (node < NN) {
            row_ptr[node] = e0 + excl;
            dis[node] = rsqrtf((float)c + 1.0f);
        }
    }
    __syncthreads();
    {
        int e = e0 + 4 * t;
        for (; e + 4 <= e1; e += 1024) {
            int r0 = rec1[e], r1 = rec1[e + 1], r2 = rec1[e + 2], r3 = rec1[e + 3];
            int p0 = atomicAdd(&cur[r0 & (BSZ - 1)], 1);
            int p1 = atomicAdd(&cur[r1 & (BSZ - 1)], 1);
            int p2 = atomicAdd(&cur[r2 & (BSZ - 1)], 1);
            int p3 = atomicAdd(&cur[r3 & (BSZ - 1)], 1);
            rec2[e0 + p0] = r0 >> BSH;
            rec2[e0 + p1] = r1 >> BSH;
            rec2[e0 + p2] = r2 >> BSH;
            rec2[e0 + p3] = r3 >> BSH;
        }
        for (int ee = e; ee < e1 && ee < e + 4; ++ee) {
            int r = rec1[ee];
            int pos = atomicAdd(&cur[r & (BSZ - 1)], 1);
            rec2[e0 + pos] = r >> BSH;
        }
    }
    if (k == 0 && t == 0) row_ptr[NN] = NE;
}

// consume one 64B x-line (16 k values) against 16 LDS W-rows (broadcast reads)
__device__ __forceinline__ void cons16(float acc[FH], float4 a0, float4 a1, float4 a2, float4 a3,
                                       const float* __restrict__ wrow) {
    float xs[16] = {a0.x, a0.y, a0.z, a0.w, a1.x, a1.y, a1.z, a1.w,
                    a2.x, a2.y, a2.z, a2.w, a3.x, a3.y, a3.z, a3.w};
    #pragma unroll
    for (int c = 0; c < 16; ++c) {
        float xv = xs[c];
        const float* w = &wrow[c * FH];
        #pragma unroll
        for (int jb = 0; jb < 4; ++jb) {
            float4 wv = *(const float4*)&w[jb * 4];
            acc[jb * 4 + 0] += xv * wv.x;
            acc[jb * 4 + 1] += xv * wv.y;
            acc[jb * 4 + 2] += xv * wv.z;
            acc[jb * 4 + 3] += xv * wv.w;
        }
    }
}

// vp1 = dis * (x @ W1): one node per thread; depth-2 pipeline; W1 in LDS (broadcast).
// Grid 1024 x 128: exactly 4 blocks/CU, 8 waves/CU.
__global__ __launch_bounds__(G1T) void k_gemm1(const float* __restrict__ x,
                                               const float* __restrict__ W1,
                                               const float* __restrict__ dis,
                                               float* __restrict__ vp1) {
    __shared__ float ws[FIN * FH];        // 32 KB
    int t = threadIdx.x;
    #pragma unroll
    for (int i = 0; i < 16; ++i)          // 16 * 128 * 4 = 8192 floats
        *(float4*)&ws[i * 512 + t * 4] = *(const float4*)&W1[i * 512 + t * 4];
    int node = blockIdx.x * NPB + t;
    bool live = (t < NPB) && (node < NN);
    int n = live ? node : NN - 1;
    const float* xr = x + (size_t)n * FIN;
    float acc[FH];
    #pragma unroll
    for (int j = 0; j < FH; ++j) acc[j] = 0.f;
    float4 A0 = *(const float4*)&xr[0],  A1 = *(const float4*)&xr[4],
           A2 = *(const float4*)&xr[8],  A3 = *(const float4*)&xr[12];
    float4 B0 = *(const float4*)&xr[16], B1 = *(const float4*)&xr[20],
           B2 = *(const float4*)&xr[24], B3 = *(const float4*)&xr[28];
    __syncthreads();
    #pragma unroll 1
    for (int k0 = 0; k0 + 48 <= FIN; k0 += 32) {
        float4 C0 = *(const float4*)&xr[k0 + 32], C1 = *(const float4*)&xr[k0 + 36],
               C2 = *(const float4*)&xr[k0 + 40], C3 = *(const float4*)&xr[k0 + 44];
        cons16(acc, A0, A1, A2, A3, &ws[k0 * FH]);
        A0 = C0; A1 = C1; A2 = C2; A3 = C3;
        float4 D0 = *(const float4*)&xr[k0 + 48], D1 = *(const float4*)&xr[k0 + 52],
               D2 = *(const float4*)&xr[k0 + 56], D3 = *(const float4*)&xr[k0 + 60];
        cons16(acc, B0, B1, B2, B3, &ws[(k0 + 16) * FH]);
        B0 = D0; B1 = D1; B2 = D2; B3 = D3;
    }
    cons16(acc, A0, A1, A2, A3, &ws[(FIN - 32) * FH]);
    cons16(acc, B0, B1, B2, B3, &ws[(FIN - 16) * FH]);
    if (live) {
        float dv = dis[node];
        #pragma unroll
        for (int jb = 0; jb < 4; ++jb)
            *(float4*)&vp1[(size_t)node * FH + jb * 4] =
                make_float4(dv * acc[jb * 4], dv * acc[jb * 4 + 1],
                            dv * acc[jb * 4 + 2], dv * acc[jb * 4 + 3]);
    }
}

// CSR register-accumulating gather, 4 lanes/node, unroll-8 independent 64B-line gathers
__device__ __forceinline__ float4 seg_gather(const int* __restrict__ recs,   // LDS copy
                                             const int* __restrict__ gsrc,   // global fallback
                                             int a, int b, int nst,
                                             const float* __restrict__ vp, int q) {
    float4 acc = make_float4(0.f, 0.f, 0.f, 0.f);
    int blds = b < nst ? b : nst;
    int i = a;
    for (; i + 8 <= blds; i += 8) {
        int r0 = recs[i],     r1 = recs[i + 1], r2 = recs[i + 2], r3 = recs[i + 3];
        int r4 = recs[i + 4], r5 = recs[i + 5], r6 = recs[i + 6], r7 = recs[i + 7];
        float4 v0 = *(const float4*)&vp[(size_t)r0 * FH + q * 4];
        float4 v1 = *(const float4*)&vp[(size_t)r1 * FH + q * 4];
        float4 v2 = *(const float4*)&vp[(size_t)r2 * FH + q * 4];
        float4 v3 = *(const float4*)&vp[(size_t)r3 * FH + q * 4];
        float4 v4 = *(const float4*)&vp[(size_t)r4 * FH + q * 4];
        float4 v5 = *(const float4*)&vp[(size_t)r5 * FH + q * 4];
        float4 v6 = *(const float4*)&vp[(size_t)r6 * FH + q * 4];
        float4 v7 = *(const float4*)&vp[(size_t)r7 * FH + q * 4];
        acc.x += ((v0.x + v1.x) + (v2.x + v3.x)) + ((v4.x + v5.x) + (v6.x + v7.x));
        acc.y += ((v0.y + v1.y) + (v2.y + v3.y)) + ((v4.y + v5.y) + (v6.y + v7.y));
        acc.z += ((v0.z + v1.z) + (v2.z + v3.z)) + ((v4.z + v5.z) + (v6.z + v7.z));
        acc.w += ((v0.w + v1.w) + (v2.w + v3.w)) + ((v4.w + v5.w) + (v6.w + v7.w));
    }
    for (; i < blds; ++i) {
        int r0 = recs[i];
        float4 v0 = *(const float4*)&vp[(size_t)r0 * FH + q * 4];
        acc.x += v0.x; acc.y += v0.y; acc.z += v0.z; acc.w += v0.w;
    }
    for (int j = (a > nst ? a : nst); j < b; ++j) {   // overflow fallback (bucket > CAP)
        int r0 = gsrc[j];
        float4 v0 = *(const float4*)&vp[(size_t)r0 * FH + q * 4];
        acc.x += v0.x; acc.y += v0.y; acc.z += v0.z; acc.w += v0.w;
    }
    return acc;
}

// layer-1: vp2[d] = dis[d] * relu(dis[d]*(sum_s vp1[s] + vp1[d]) + b1)
__global__ __launch_bounds__(256) void k_agg1(const int* __restrict__ rec2,
                                              const int* __restrict__ bstart,
                                              const int* __restrict__ row_ptr,
                                              const float* __restrict__ dis,
                                              const float* __restrict__ vp1,
                                              const float* __restrict__ b1,
                                              float* __restrict__ vp2) {
    __shared__ int recs[CAP];                 // 16 KB
    int t = threadIdx.x, k = blockIdx.x;
    int e0 = bstart[k], e1 = bstart[k + 1];
    int len = e1 - e0, nst = len < CAP ? len : CAP;
    for (int i = t; i < nst; i += 256) recs[i] = rec2[e0 + i];
    __syncthreads();                          // no barriers after: early-exit safe
    int slot = t >> 2, q = t & 3;
    int node = k * BSZ + slot;
    if (node >= NN) return;
    int a = row_ptr[node] - e0;
    int b = row_ptr[node + 1] - e0;
    float4 acc = seg_gather(recs, rec2 + e0, a, b, nst, vp1, q);
    float dv = dis[node];
    float4 self = *(const float4*)&vp1[(size_t)node * FH + q * 4];
    float4 bb   = *(const float4*)&b1[q * 4];
    float4 o;
    o.x = dv * fmaxf(dv * (acc.x + self.x) + bb.x, 0.f);
    o.y = dv * fmaxf(dv * (acc.y + self.y) + bb.y, 0.f);
    o.z = dv * fmaxf(dv * (acc.z + self.z) + bb.z, 0.f);
    o.w = dv * fmaxf(dv * (acc.w + self.w) + bb.w, 0.f);
    *(float4*)&vp2[(size_t)node * FH + q * 4] = o;
}

// layer-2: a16 = dis[d]*(sum_s vp2[s] + vp2[d]); out = relu(a16 @ W2 + b2)
__global__ __launch_bounds__(256) void k_agg2(const int* __restrict__ rec2,
                                              const int* __restrict__ bstart,
                                              const int* __restrict__ row_ptr,
                                              const float* __restrict__ dis,
                                              const float* __restrict__ vp2,
                                              const float* __restrict__ W2,
                                              const float* __restrict__ b2,
                                              float* __restrict__ out) {
    __shared__ int   recs[CAP];               // 16 KB
    __shared__ float a16[BSZ * FH];           // 4 KB
    __shared__ float ws[FH * FOUT];           // 4 KB
    int t = threadIdx.x, k = blockIdx.x;
    *(float4*)&ws[t * 4] = *(const float4*)&W2[t * 4];   // 256*4 = FH*FOUT
    int e0 = bstart[k], e1 = bstart[k + 1];
    int len = e1 - e0, nst = len < CAP ? len : CAP;
    for (int i = t; i < nst; i += 256) recs[i] = rec2[e0 + i];
    __syncthreads();
    int slot = t >> 2, q = t & 3;
    int node = k * BSZ + slot;
    float4 r = make_float4(0.f, 0.f, 0.f, 0.f);
    if (node < NN) {
        int a = row_ptr[node] - e0;
        int b = row_ptr[node + 1] - e0;
        float4 acc = seg_gather(recs, rec2 + e0, a, b, nst, vp2, q);
        float dv = dis[node];
        float4 self = *(const float4*)&vp2[(size_t)node * FH + q * 4];
        r.x = dv * (acc.x + self.x);
        r.y = dv * (acc.y + self.y);
        r.z = dv * (acc.z + self.z);
        r.w = dv * (acc.w + self.w);
    }
    *(float4*)&a16[slot * FH + q * 4] = r;
    __syncthreads();
    int j = t & 63;
    float bj = b2[j];
    float wreg[FH];
    #pragma unroll
    for (int kk = 0; kk < FH; ++kk) wreg[kk] = ws[kk * FOUT + j];
    for (int n = t >> 6; n < BSZ; n += 4) {
        int node2 = k * BSZ + n;
        if (node2 >= NN) break;
        const float* ar = &a16[n * FH];
        float s = 0.f;
        #pragma unroll
        for (int kk = 0; kk < FH; ++kk) s += ar[kk] * wreg[kk];
        out[(size_t)node2 * FOUT + j] = fmaxf(s + bj, 0.f);
    }
}

extern "C" void kernel_launch(void* const* d_in, const int* in_sizes, int n_in,
                              void* d_out, int out_size, void* d_ws, size_t ws_size,
                              hipStream_t stream) {
    const float* x  = (const float*)d_in[0];
    const int*   ei = (const int*)d_in[1];
    const float* W1 = (const float*)d_in[2];
    const float* b1 = (const float*)d_in[3];
    const float* W2 = (const float*)d_in[4];
    const float* b2 = (const float*)d_in[5];
    float* out = (float*)d_out;

    // workspace (~29.6 MB). rec1's 12.8MB is dead after k_sort2 and is reused
    // for vp1 (6.4MB) + vp2 (6.4MB): stream-ordered, no overlap hazard.
    char* p = (char*)d_ws;
    int*   M       = (int*)p;    p += (size_t)K * NB * 4;      // 3.2 MB
    int*   btot    = (int*)p;    p += 2048 * 4;
    int*   bstart  = (int*)p;    p += 2048 * 4;
    char*  bufA    = p;          p += (size_t)NE * 4;          // 12.8 MB (rec1 -> vp1+vp2)
    int*   rec2    = (int*)p;    p += (size_t)NE * 4;          // 12.8 MB
    int*   row_ptr = (int*)p;    p += 100032 * 4;              // 0.4 MB
    float* dis     = (float*)p;  p += 100032 * 4;              // 0.4 MB

    int*   rec1 = (int*)bufA;
    float* vp1  = (float*)bufA;
    float* vp2  = (float*)(bufA + (size_t)NN * FH * 4);

    k_cnt     <<<NB, 256, 0, stream>>>(ei, M);
    k_scanM   <<<K, 256, 0, stream>>>(M, btot);
    k_scanB   <<<1, 1024, 0, stream>>>(btot, bstart);
    k_scatter2<<<NB, 256, 0, stream>>>(ei, M, bstart, rec1);
    k_sort2   <<<K, 256, 0, stream>>>(rec1, bstart, rec2, row_ptr, dis);

    k_gemm1   <<<G1B, G1T, 0, stream>>>(x, W1, dis, vp1);
    k_agg1    <<<K, 256, 0, stream>>>(rec2, bstart, row_ptr, dis, vp1, b1, vp2);
    k_agg2    <<<K, 256, 0, stream>>>(rec2, bstart, row_ptr, dis, vp2, W2, b2, out);
}